// Round 6
// baseline (283.844 us; speedup 1.0000x reference)
//
#include <hip/hip_runtime.h>

#define IN_DIM 128
#define HID    256
#define NCLS   40
#define BSHIFT 8
#define BSZ    256     // nodes per bucket
#define MAXNB  256     // max buckets (N <= 65536)
#define CHUNK  4096    // edges per scatter block

static inline size_t align256(size_t x) { return (x + 255) & ~(size_t)255; }

__device__ inline unsigned pack_bf16x2(float x, float y) {
    unsigned xb = __float_as_uint(x), yb = __float_as_uint(y);
    unsigned lo = (xb + 0x7fffu + ((xb >> 16) & 1u)) >> 16;
    unsigned hi = (yb + 0x7fffu + ((yb >> 16) & 1u)) >> 16;
    return lo | (hi << 16);
}
__device__ inline unsigned short f2bf(float x) {
    unsigned b = __float_as_uint(x);
    return (unsigned short)((b + 0x7fffu + ((b >> 16) & 1u)) >> 16);
}
__device__ inline float lo16(unsigned u) { return __uint_as_float(u << 16); }
__device__ inline float hi16(unsigned u) { return __uint_as_float(u & 0xffff0000u); }

// ---- K1: bucket histogram ----
__global__ __launch_bounds__(256) void bucket_count_kernel(
        const int* __restrict__ dst, int* __restrict__ bucketCnt, int E, int NB) {
    __shared__ int hist[MAXNB];
    int t = threadIdx.x;
    hist[t] = 0;
    __syncthreads();
    int start = blockIdx.x * CHUNK;
    int cnt = min(CHUNK, E - start);
    for (int i = t; i < cnt; i += 256) atomicAdd(&hist[dst[start + i] >> BSHIFT], 1);
    __syncthreads();
    if (t < NB && hist[t]) atomicAdd(&bucketCnt[t], hist[t]);
}

// ---- K2: scan bucket totals ----
__global__ __launch_bounds__(256) void bucket_scan_kernel(
        const int* __restrict__ bucketCnt, int* __restrict__ bucketBase,
        int* __restrict__ bucketCursor, int* __restrict__ offs, int NB, int N) {
    int t = threadIdx.x, lane = t & 63, wave = t >> 6;
    int v = (t < NB) ? bucketCnt[t] : 0;
    int s = v;
    for (int off = 1; off < 64; off <<= 1) {
        int u = __shfl_up(s, off, 64);
        if (lane >= off) s += u;
    }
    __shared__ int wsum[4];
    if (lane == 63) wsum[wave] = s;
    __syncthreads();
    if (t == 0) {
        int c = 0;
        for (int i = 0; i < 4; ++i) { int x = wsum[i]; wsum[i] = c; c += x; }
    }
    __syncthreads();
    int incl = wsum[wave] + s;
    int excl = incl - v;
    if (t < NB) { bucketBase[t] = excl; bucketCursor[t] = excl; }
    if (t == NB - 1) { bucketBase[NB] = incl; offs[N] = incl; }
}

// ---- K3: bucket-ordered scatter via LDS binning ----
__global__ __launch_bounds__(256) void bucket_scatter_kernel(
        const int* __restrict__ src, const int* __restrict__ dst,
        int* __restrict__ bucketCursor, int2* __restrict__ ebuf, int E) {
    __shared__ int hist[MAXNB], lofs[MAXNB], lcur[MAXNB], gbase[MAXNB];
    __shared__ int2 bin[CHUNK];
    int t = threadIdx.x, lane = t & 63, wave = t >> 6;
    int start = blockIdx.x * CHUNK;
    int cnt = min(CHUNK, E - start);
    hist[t] = 0;
    __syncthreads();
    for (int i = t; i < cnt; i += 256) atomicAdd(&hist[dst[start + i] >> BSHIFT], 1);
    __syncthreads();
    int v = hist[t];
    int s = v;
    for (int off = 1; off < 64; off <<= 1) {
        int u = __shfl_up(s, off, 64);
        if (lane >= off) s += u;
    }
    __shared__ int wsum[4];
    if (lane == 63) wsum[wave] = s;
    __syncthreads();
    if (t == 0) {
        int c = 0;
        for (int i = 0; i < 4; ++i) { int x = wsum[i]; wsum[i] = c; c += x; }
    }
    __syncthreads();
    int excl = wsum[wave] + s - v;
    lofs[t] = excl; lcur[t] = excl;
    if (v) gbase[t] = atomicAdd(&bucketCursor[t], v);
    __syncthreads();
    for (int i = t; i < cnt; i += 256) {
        int s0 = src[start + i], d0 = dst[start + i];
        int r = atomicAdd(&lcur[d0 >> BSHIFT], 1);
        bin[r] = make_int2(s0, d0);
    }
    __syncthreads();
    for (int i = t; i < cnt; i += 256) {
        int2 e = bin[i];
        int b = e.y >> BSHIFT;
        ebuf[gbase[b] + i - lofs[b]] = e;
    }
}

// ---- K4: per-bucket degrees -> offs, norm ----
__global__ __launch_bounds__(256) void build_norm_kernel(
        const int2* __restrict__ ebuf, const int* __restrict__ bucketBase,
        int* __restrict__ offs, float* __restrict__ norm, int N) {
    __shared__ int hist[BSZ];
    int b = blockIdx.x, t = threadIdx.x, lane = t & 63, wave = t >> 6;
    hist[t] = 0;
    __syncthreads();
    int segS = bucketBase[b], segE = bucketBase[b + 1];
    for (int i = segS + t; i < segE; i += 256) atomicAdd(&hist[ebuf[i].y & (BSZ - 1)], 1);
    __syncthreads();
    int v = hist[t];
    int s = v;
    for (int off = 1; off < 64; off <<= 1) {
        int u = __shfl_up(s, off, 64);
        if (lane >= off) s += u;
    }
    __shared__ int wsum[4];
    if (lane == 63) wsum[wave] = s;
    __syncthreads();
    if (t == 0) {
        int c = 0;
        for (int i = 0; i < 4; ++i) { int x = wsum[i]; wsum[i] = c; c += x; }
    }
    __syncthreads();
    int excl = wsum[wave] + s - v;
    int node = b * BSZ + t;
    if (node < N) {
        offs[node] = segS + excl;
        norm[node] = rsqrtf((float)(v > 0 ? v : 1));
    }
}

// ---- K5: per-bucket exact CSR placement with weights ----
__global__ __launch_bounds__(256) void build_csr_kernel(
        const int2* __restrict__ ebuf, const int* __restrict__ bucketBase,
        const int* __restrict__ offs, const float* __restrict__ norm,
        int2* __restrict__ csr, int N) {
    __shared__ int lcur[BSZ];
    __shared__ float snorm[BSZ];
    int b = blockIdx.x, t = threadIdx.x;
    int node = b * BSZ + t;
    lcur[t] = (node < N) ? offs[node] : 0;
    snorm[t] = (node < N) ? norm[node] : 0.f;
    __syncthreads();
    int segS = bucketBase[b], segE = bucketBase[b + 1];
    for (int i = segS + t; i < segE; i += 256) {
        int2 e = ebuf[i];
        int li = e.y & (BSZ - 1);
        float w = norm[e.x] * snorm[li];
        int p = atomicAdd(&lcur[li], 1);
        csr[p] = make_int2(e.x, __float_as_int(w));
    }
}

// ---- prep: feat fp32->bf16 cast + weight transpose/convert, one kernel ----
__global__ void prep_kernel(const float* __restrict__ feat, unsigned* __restrict__ xb,
                            const float* __restrict__ W1, const float* __restrict__ W2,
                            unsigned short* __restrict__ W1T, unsigned short* __restrict__ W2T,
                            int nfeat2) {
    int i = blockIdx.x * blockDim.x + threadIdx.x;
    if (i < nfeat2) {
        float2 f = *(const float2*)(feat + (size_t)i * 2);
        xb[i] = pack_bf16x2(f.x, f.y);
        return;
    }
    int j = i - nfeat2;
    if (j < 256 * 128) {                       // W1T[n][k] = W1[k][n]
        int n = j >> 7, k = j & 127;
        W1T[j] = f2bf(W1[k * 256 + n]);
        return;
    }
    int k2 = j - 256 * 128;
    if (k2 < 48 * 256) {                       // W2T[c][k] = W2[k][c], pad c to 48
        int c = k2 >> 8, kk = k2 & 255;
        W2T[k2] = (c < 40) ? f2bf(W2[kk * 40 + c]) : (unsigned short)0;
    }
}

// ---- propagation (steps 1,2): wave per node, quarter-wave dwordx4 gathers ----
__global__ __launch_bounds__(256) void prop_kernel(
        const unsigned* __restrict__ xin, unsigned* __restrict__ xout,
        const int* __restrict__ offs, const int2* __restrict__ csr, int N) {
    int t = threadIdx.x;
    int wv = t >> 6, lane = t & 63;
    int q = lane >> 4, ql = lane & 15;
    int v = blockIdx.x * 4 + wv;
    if (v >= N) return;
    __shared__ int2 sIW[4][64];
    int start = offs[v], end = offs[v + 1];
    float a0 = 0.f, a1 = 0.f, a2 = 0.f, a3 = 0.f;
    float a4 = 0.f, a5 = 0.f, a6 = 0.f, a7 = 0.f;
    for (int k = start; k < end; k += 64) {
        int cnt = min(64, end - k);
        if (lane < cnt) sIW[wv][lane] = csr[k + lane];   // same-wave LDS: ordered
        int j = 0;
        for (; j + 16 <= cnt; j += 16) {
            uint4 d[4]; float w[4];
#pragma unroll
            for (int u = 0; u < 4; ++u) {
                int2 e = sIW[wv][j + 4 * u + q];
                w[u] = __int_as_float(e.y);
                d[u] = *(const uint4*)(xin + (size_t)e.x * 64 + ql * 4);
            }
#pragma unroll
            for (int u = 0; u < 4; ++u) {
                a0 += lo16(d[u].x) * w[u]; a1 += hi16(d[u].x) * w[u];
                a2 += lo16(d[u].y) * w[u]; a3 += hi16(d[u].y) * w[u];
                a4 += lo16(d[u].z) * w[u]; a5 += hi16(d[u].z) * w[u];
                a6 += lo16(d[u].w) * w[u]; a7 += hi16(d[u].w) * w[u];
            }
        }
        for (; j < cnt; j += 4) {
            int idx = j + q;
            float w = 0.f; uint4 d = make_uint4(0u, 0u, 0u, 0u);
            if (idx < cnt) {
                int2 e = sIW[wv][idx];
                w = __int_as_float(e.y);
                d = *(const uint4*)(xin + (size_t)e.x * 64 + ql * 4);
            }
            a0 += lo16(d.x) * w; a1 += hi16(d.x) * w;
            a2 += lo16(d.y) * w; a3 += hi16(d.y) * w;
            a4 += lo16(d.z) * w; a5 += hi16(d.z) * w;
            a6 += lo16(d.w) * w; a7 += hi16(d.w) * w;
        }
    }
    a0 += __shfl_xor(a0, 16, 64); a0 += __shfl_xor(a0, 32, 64);
    a1 += __shfl_xor(a1, 16, 64); a1 += __shfl_xor(a1, 32, 64);
    a2 += __shfl_xor(a2, 16, 64); a2 += __shfl_xor(a2, 32, 64);
    a3 += __shfl_xor(a3, 16, 64); a3 += __shfl_xor(a3, 32, 64);
    a4 += __shfl_xor(a4, 16, 64); a4 += __shfl_xor(a4, 32, 64);
    a5 += __shfl_xor(a5, 16, 64); a5 += __shfl_xor(a5, 32, 64);
    a6 += __shfl_xor(a6, 16, 64); a6 += __shfl_xor(a6, 32, 64);
    a7 += __shfl_xor(a7, 16, 64); a7 += __shfl_xor(a7, 32, 64);
    if (q == 0) {
        uint4 o;
        o.x = pack_bf16x2(a0, a1); o.y = pack_bf16x2(a2, a3);
        o.z = pack_bf16x2(a4, a5); o.w = pack_bf16x2(a6, a7);
        *(uint4*)(xout + (size_t)v * 64 + ql * 4) = o;
    }
}

// ---- fused prop3 + MLP + log_softmax: 16 nodes per block ----
typedef __attribute__((ext_vector_type(8))) short bf16x8;
typedef __attribute__((ext_vector_type(4))) float f32x4;

#define SA_STRIDE 136
#define SH_STRIDE 264

__global__ __launch_bounds__(256) void prop3_mlp_kernel(
        const unsigned* __restrict__ x2,                 // gather source (+ own row)
        const float* __restrict__ feat, const unsigned* __restrict__ x1,
        const int* __restrict__ offs, const int2* __restrict__ csr,
        const unsigned short* __restrict__ W1T, const float* __restrict__ b1,
        const unsigned short* __restrict__ W2T, const float* __restrict__ b2,
        float* __restrict__ out, int N) {
    __shared__ unsigned short sA[16 * SA_STRIDE];
    __shared__ unsigned short sH[16 * SH_STRIDE];
    __shared__ int2 sIW[4][64];
    int t = threadIdx.x, wv = t >> 6, lane = t & 63;
    int q = lane >> 4, ql = lane & 15;
    int l15 = ql, lq = q;
    int base = blockIdx.x * 16;

    // preload this wave's W1 fragments (hid range [wv*64, wv*64+64))
    bf16x8 w1f[4][4];
#pragma unroll
    for (int s = 0; s < 4; ++s)
#pragma unroll
        for (int ht = 0; ht < 4; ++ht)
            w1f[s][ht] = *(const bf16x8*)(W1T + ((wv * 64 + ht * 16 + l15) * 128 + s * 32 + lq * 8));

    // ---- phase A: gather x3 for 4 nodes, combine with feat+x1+x2, stage A tile ----
    for (int nd = 0; nd < 4; ++nd) {
        int v = base + wv * 4 + nd;
        int ln = wv * 4 + nd;
        float a0 = 0.f, a1 = 0.f, a2 = 0.f, a3 = 0.f;
        float a4 = 0.f, a5 = 0.f, a6 = 0.f, a7 = 0.f;
        if (v < N) {
            int start = offs[v], end = offs[v + 1];
            for (int k = start; k < end; k += 64) {
                int cnt = min(64, end - k);
                if (lane < cnt) sIW[wv][lane] = csr[k + lane];
                int j = 0;
                for (; j + 16 <= cnt; j += 16) {
                    uint4 d[4]; float w[4];
#pragma unroll
                    for (int u = 0; u < 4; ++u) {
                        int2 e = sIW[wv][j + 4 * u + q];
                        w[u] = __int_as_float(e.y);
                        d[u] = *(const uint4*)(x2 + (size_t)e.x * 64 + ql * 4);
                    }
#pragma unroll
                    for (int u = 0; u < 4; ++u) {
                        a0 += lo16(d[u].x) * w[u]; a1 += hi16(d[u].x) * w[u];
                        a2 += lo16(d[u].y) * w[u]; a3 += hi16(d[u].y) * w[u];
                        a4 += lo16(d[u].z) * w[u]; a5 += hi16(d[u].z) * w[u];
                        a6 += lo16(d[u].w) * w[u]; a7 += hi16(d[u].w) * w[u];
                    }
                }
                for (; j < cnt; j += 4) {
                    int idx = j + q;
                    float w = 0.f; uint4 d = make_uint4(0u, 0u, 0u, 0u);
                    if (idx < cnt) {
                        int2 e = sIW[wv][idx];
                        w = __int_as_float(e.y);
                        d = *(const uint4*)(x2 + (size_t)e.x * 64 + ql * 4);
                    }
                    a0 += lo16(d.x) * w; a1 += hi16(d.x) * w;
                    a2 += lo16(d.y) * w; a3 += hi16(d.y) * w;
                    a4 += lo16(d.z) * w; a5 += hi16(d.z) * w;
                    a6 += lo16(d.w) * w; a7 += hi16(d.w) * w;
                }
            }
        }
        a0 += __shfl_xor(a0, 16, 64); a0 += __shfl_xor(a0, 32, 64);
        a1 += __shfl_xor(a1, 16, 64); a1 += __shfl_xor(a1, 32, 64);
        a2 += __shfl_xor(a2, 16, 64); a2 += __shfl_xor(a2, 32, 64);
        a3 += __shfl_xor(a3, 16, 64); a3 += __shfl_xor(a3, 32, 64);
        a4 += __shfl_xor(a4, 16, 64); a4 += __shfl_xor(a4, 32, 64);
        a5 += __shfl_xor(a5, 16, 64); a5 += __shfl_xor(a5, 32, 64);
        a6 += __shfl_xor(a6, 16, 64); a6 += __shfl_xor(a6, 32, 64);
        a7 += __shfl_xor(a7, 16, 64); a7 += __shfl_xor(a7, 32, 64);
        if (q == 0) {
            uint4 o = make_uint4(0u, 0u, 0u, 0u);
            if (v < N) {
                size_t fo = (size_t)v * 128 + ql * 8;
                float4 f0 = *(const float4*)(feat + fo);
                float4 f1 = *(const float4*)(feat + fo + 4);
                uint4 u1 = *(const uint4*)(x1 + (size_t)v * 64 + ql * 4);
                uint4 u2 = *(const uint4*)(x2 + (size_t)v * 64 + ql * 4);
                float s0 = (f0.x + lo16(u1.x) + lo16(u2.x) + a0) * 0.25f;
                float s1 = (f0.y + hi16(u1.x) + hi16(u2.x) + a1) * 0.25f;
                float s2 = (f0.z + lo16(u1.y) + lo16(u2.y) + a2) * 0.25f;
                float s3 = (f0.w + hi16(u1.y) + hi16(u2.y) + a3) * 0.25f;
                float s4 = (f1.x + lo16(u1.z) + lo16(u2.z) + a4) * 0.25f;
                float s5 = (f1.y + hi16(u1.z) + hi16(u2.z) + a5) * 0.25f;
                float s6 = (f1.z + lo16(u1.w) + lo16(u2.w) + a6) * 0.25f;
                float s7 = (f1.w + hi16(u1.w) + hi16(u2.w) + a7) * 0.25f;
                o.x = pack_bf16x2(s0, s1); o.y = pack_bf16x2(s2, s3);
                o.z = pack_bf16x2(s4, s5); o.w = pack_bf16x2(s6, s7);
            }
            *(uint4*)&sA[ln * SA_STRIDE + ql * 8] = o;
        }
    }
    __syncthreads();

    // ---- phase B: matmul1, wave wv computes hid [wv*64, wv*64+64) for 16 nodes ----
    f32x4 acc[4];
#pragma unroll
    for (int ht = 0; ht < 4; ++ht) acc[ht] = (f32x4){0.f, 0.f, 0.f, 0.f};
#pragma unroll
    for (int s = 0; s < 4; ++s) {
        bf16x8 afr = *(const bf16x8*)&sA[l15 * SA_STRIDE + s * 32 + lq * 8];
#pragma unroll
        for (int ht = 0; ht < 4; ++ht)
            acc[ht] = __builtin_amdgcn_mfma_f32_16x16x32_bf16(afr, w1f[s][ht], acc[ht], 0, 0, 0);
    }
#pragma unroll
    for (int ht = 0; ht < 4; ++ht) {
        int hid = wv * 64 + ht * 16 + l15;
        float bb = b1[hid];
#pragma unroll
        for (int r = 0; r < 4; ++r) {
            int node = lq * 4 + r;
            sH[node * SH_STRIDE + hid] = f2bf(fmaxf(acc[ht][r] + bb, 0.f));
        }
    }
    __syncthreads();
    if (wv != 0) return;

    // ---- phase C (wave 0): matmul2 + log_softmax + out ----
    bf16x8 w2f[8][3];
#pragma unroll
    for (int s = 0; s < 8; ++s)
#pragma unroll
        for (int ct = 0; ct < 3; ++ct)
            w2f[s][ct] = *(const bf16x8*)(W2T + ((ct * 16 + l15) * 256 + s * 32 + lq * 8));

    f32x4 acc2[3];
#pragma unroll
    for (int ct = 0; ct < 3; ++ct) acc2[ct] = (f32x4){0.f, 0.f, 0.f, 0.f};
#pragma unroll
    for (int s = 0; s < 8; ++s) {
        bf16x8 afr = *(const bf16x8*)&sH[l15 * SH_STRIDE + s * 32 + lq * 8];
#pragma unroll
        for (int ct = 0; ct < 3; ++ct)
            acc2[ct] = __builtin_amdgcn_mfma_f32_16x16x32_bf16(afr, w2f[s][ct], acc2[ct], 0, 0, 0);
    }

    float lg[3][4];
#pragma unroll
    for (int ct = 0; ct < 3; ++ct) {
        int c = ct * 16 + l15;
        float bb = (c < NCLS) ? b2[c] : 0.f;
#pragma unroll
        for (int r = 0; r < 4; ++r) lg[ct][r] = acc2[ct][r] + bb;
    }
#pragma unroll
    for (int r = 0; r < 4; ++r) {
        float m = fmaxf(lg[0][r], lg[1][r]);
        if (l15 < 8) m = fmaxf(m, lg[2][r]);
        for (int off = 1; off < 16; off <<= 1) m = fmaxf(m, __shfl_xor(m, off, 64));
        float ssum = __expf(lg[0][r] - m) + __expf(lg[1][r] - m) +
                     ((l15 < 8) ? __expf(lg[2][r] - m) : 0.f);
        for (int off = 1; off < 16; off <<= 1) ssum += __shfl_xor(ssum, off, 64);
        float ls = m + __logf(ssum);
        int node = base + lq * 4 + r;
        if (node < N) {
#pragma unroll
            for (int ct = 0; ct < 3; ++ct) {
                int c = ct * 16 + l15;
                if (c < NCLS) out[(size_t)node * NCLS + c] = lg[ct][r] - ls;
            }
        }
    }
}

extern "C" void kernel_launch(void* const* d_in, const int* in_sizes, int n_in,
                              void* d_out, int out_size, void* d_ws, size_t ws_size,
                              hipStream_t stream) {
    const float* feat = (const float*)d_in[0];
    const int*   src  = (const int*)d_in[1];
    const int*   dst  = (const int*)d_in[2];
    const float* W1   = (const float*)d_in[3];
    const float* b1   = (const float*)d_in[4];
    const float* W2   = (const float*)d_in[5];
    const float* b2   = (const float*)d_in[6];
    float* out = (float*)d_out;

    int N = in_sizes[0] / IN_DIM;
    int E = in_sizes[1];
    int NB = (N + BSZ - 1) / BSZ;

    char* ws = (char*)d_ws;
    size_t off = 0;
    float* norm   = (float*)(ws + off); off += align256((size_t)N * 4);
    int*   offs   = (int*)(ws + off);   off += align256((size_t)(N + 1) * 4);
    int*   bBase  = (int*)(ws + off);   off += align256((size_t)(MAXNB + 1) * 4);
    int*   bCur   = (int*)(ws + off);   off += align256((size_t)MAXNB * 4);
    int*   bCnt   = (int*)(ws + off);   off += align256((size_t)MAXNB * 4);
    int2*  csr    = (int2*)(ws + off);  off += align256((size_t)E * 8);
    unsigned* x0  = (unsigned*)(ws + off); off += align256((size_t)N * 64 * 4);
    unsigned* x1  = (unsigned*)(ws + off); off += align256((size_t)N * 64 * 4);
    unsigned* x2  = (unsigned*)(ws + off); off += align256((size_t)N * 64 * 4);
    unsigned short* W1T = (unsigned short*)(ws + off); off += align256((size_t)256 * 128 * 2);
    unsigned short* W2T = (unsigned short*)(ws + off); off += align256((size_t)48 * 256 * 2);
    (void)ws_size;
    int2* ebuf = (int2*)x1;   // alias: ebuf dead (after build_csr) before prop1 writes x1

    hipMemsetAsync(bCnt, 0, (size_t)MAXNB * 4, stream);

    int echunks = (E + CHUNK - 1) / CHUNK;
    bucket_count_kernel<<<echunks, 256, 0, stream>>>(dst, bCnt, E, NB);
    bucket_scan_kernel<<<1, 256, 0, stream>>>(bCnt, bBase, bCur, offs, NB, N);
    bucket_scatter_kernel<<<echunks, 256, 0, stream>>>(src, dst, bCur, ebuf, E);
    build_norm_kernel<<<NB, 256, 0, stream>>>(ebuf, bBase, offs, norm, N);
    build_csr_kernel<<<NB, 256, 0, stream>>>(ebuf, bBase, offs, norm, csr, N);

    int nprep = N * 64 + 256 * 128 + 48 * 256;
    prep_kernel<<<(nprep + 255) / 256, 256, 0, stream>>>(feat, x0, W1, W2, W1T, W2T, N * 64);

    int pb = (N + 3) / 4;
    prop_kernel<<<pb, 256, 0, stream>>>(x0, x1, offs, csr, N);
    prop_kernel<<<pb, 256, 0, stream>>>(x1, x2, offs, csr, N);
    prop3_mlp_kernel<<<(N + 15) / 16, 256, 0, stream>>>(x2, feat, x1, offs, csr,
                                                        W1T, b1, W2T, b2, out, N);
}

// Round 7
// 262.114 us; speedup vs baseline: 1.0829x; 1.0829x over previous
//
#include <hip/hip_runtime.h>

#define IN_DIM 128
#define HID    256
#define NCLS   40
#define BSHIFT 8
#define BSZ    256     // nodes per bucket
#define MAXNB  256     // max buckets (N <= 65536)
#define CHUNK  4096    // edges per scatter block

static inline size_t align256(size_t x) { return (x + 255) & ~(size_t)255; }

__device__ inline unsigned pack_bf16x2(float x, float y) {
    unsigned xb = __float_as_uint(x), yb = __float_as_uint(y);
    unsigned lo = (xb + 0x7fffu + ((xb >> 16) & 1u)) >> 16;
    unsigned hi = (yb + 0x7fffu + ((yb >> 16) & 1u)) >> 16;
    return lo | (hi << 16);
}
__device__ inline unsigned short f2bf(float x) {
    unsigned b = __float_as_uint(x);
    return (unsigned short)((b + 0x7fffu + ((b >> 16) & 1u)) >> 16);
}
__device__ inline float lo16(unsigned u) { return __uint_as_float(u << 16); }
__device__ inline float hi16(unsigned u) { return __uint_as_float(u & 0xffff0000u); }

// ---- K1: bucket histogram ----
__global__ __launch_bounds__(256) void bucket_count_kernel(
        const int* __restrict__ dst, int* __restrict__ bucketCnt, int E, int NB) {
    __shared__ int hist[MAXNB];
    int t = threadIdx.x;
    hist[t] = 0;
    __syncthreads();
    int start = blockIdx.x * CHUNK;
    int cnt = min(CHUNK, E - start);
    for (int i = t; i < cnt; i += 256) atomicAdd(&hist[dst[start + i] >> BSHIFT], 1);
    __syncthreads();
    if (t < NB && hist[t]) atomicAdd(&bucketCnt[t], hist[t]);
}

// ---- K2: scan bucket totals ----
__global__ __launch_bounds__(256) void bucket_scan_kernel(
        const int* __restrict__ bucketCnt, int* __restrict__ bucketBase,
        int* __restrict__ bucketCursor, int* __restrict__ offs, int NB, int N) {
    int t = threadIdx.x, lane = t & 63, wave = t >> 6;
    int v = (t < NB) ? bucketCnt[t] : 0;
    int s = v;
    for (int off = 1; off < 64; off <<= 1) {
        int u = __shfl_up(s, off, 64);
        if (lane >= off) s += u;
    }
    __shared__ int wsum[4];
    if (lane == 63) wsum[wave] = s;
    __syncthreads();
    if (t == 0) {
        int c = 0;
        for (int i = 0; i < 4; ++i) { int x = wsum[i]; wsum[i] = c; c += x; }
    }
    __syncthreads();
    int incl = wsum[wave] + s;
    int excl = incl - v;
    if (t < NB) { bucketBase[t] = excl; bucketCursor[t] = excl; }
    if (t == NB - 1) { bucketBase[NB] = incl; offs[N] = incl; }
}

// ---- K3: bucket-ordered scatter via LDS binning ----
__global__ __launch_bounds__(256) void bucket_scatter_kernel(
        const int* __restrict__ src, const int* __restrict__ dst,
        int* __restrict__ bucketCursor, int2* __restrict__ ebuf, int E) {
    __shared__ int hist[MAXNB], lofs[MAXNB], lcur[MAXNB], gbase[MAXNB];
    __shared__ int2 bin[CHUNK];
    int t = threadIdx.x, lane = t & 63, wave = t >> 6;
    int start = blockIdx.x * CHUNK;
    int cnt = min(CHUNK, E - start);
    hist[t] = 0;
    __syncthreads();
    for (int i = t; i < cnt; i += 256) atomicAdd(&hist[dst[start + i] >> BSHIFT], 1);
    __syncthreads();
    int v = hist[t];
    int s = v;
    for (int off = 1; off < 64; off <<= 1) {
        int u = __shfl_up(s, off, 64);
        if (lane >= off) s += u;
    }
    __shared__ int wsum[4];
    if (lane == 63) wsum[wave] = s;
    __syncthreads();
    if (t == 0) {
        int c = 0;
        for (int i = 0; i < 4; ++i) { int x = wsum[i]; wsum[i] = c; c += x; }
    }
    __syncthreads();
    int excl = wsum[wave] + s - v;
    lofs[t] = excl; lcur[t] = excl;
    if (v) gbase[t] = atomicAdd(&bucketCursor[t], v);
    __syncthreads();
    for (int i = t; i < cnt; i += 256) {
        int s0 = src[start + i], d0 = dst[start + i];
        int r = atomicAdd(&lcur[d0 >> BSHIFT], 1);
        bin[r] = make_int2(s0, d0);
    }
    __syncthreads();
    for (int i = t; i < cnt; i += 256) {
        int2 e = bin[i];
        int b = e.y >> BSHIFT;
        ebuf[gbase[b] + i - lofs[b]] = e;
    }
}

// ---- K4: per-bucket degrees -> offs, norm ----
__global__ __launch_bounds__(256) void build_norm_kernel(
        const int2* __restrict__ ebuf, const int* __restrict__ bucketBase,
        int* __restrict__ offs, float* __restrict__ norm, int N) {
    __shared__ int hist[BSZ];
    int b = blockIdx.x, t = threadIdx.x, lane = t & 63, wave = t >> 6;
    hist[t] = 0;
    __syncthreads();
    int segS = bucketBase[b], segE = bucketBase[b + 1];
    for (int i = segS + t; i < segE; i += 256) atomicAdd(&hist[ebuf[i].y & (BSZ - 1)], 1);
    __syncthreads();
    int v = hist[t];
    int s = v;
    for (int off = 1; off < 64; off <<= 1) {
        int u = __shfl_up(s, off, 64);
        if (lane >= off) s += u;
    }
    __shared__ int wsum[4];
    if (lane == 63) wsum[wave] = s;
    __syncthreads();
    if (t == 0) {
        int c = 0;
        for (int i = 0; i < 4; ++i) { int x = wsum[i]; wsum[i] = c; c += x; }
    }
    __syncthreads();
    int excl = wsum[wave] + s - v;
    int node = b * BSZ + t;
    if (node < N) {
        offs[node] = segS + excl;
        norm[node] = rsqrtf((float)(v > 0 ? v : 1));
    }
}

// ---- K5: per-bucket exact CSR placement with weights ----
__global__ __launch_bounds__(256) void build_csr_kernel(
        const int2* __restrict__ ebuf, const int* __restrict__ bucketBase,
        const int* __restrict__ offs, const float* __restrict__ norm,
        int2* __restrict__ csr, int N) {
    __shared__ int lcur[BSZ];
    __shared__ float snorm[BSZ];
    int b = blockIdx.x, t = threadIdx.x;
    int node = b * BSZ + t;
    lcur[t] = (node < N) ? offs[node] : 0;
    snorm[t] = (node < N) ? norm[node] : 0.f;
    __syncthreads();
    int segS = bucketBase[b], segE = bucketBase[b + 1];
    for (int i = segS + t; i < segE; i += 256) {
        int2 e = ebuf[i];
        int li = e.y & (BSZ - 1);
        float w = norm[e.x] * snorm[li];
        int p = atomicAdd(&lcur[li], 1);
        csr[p] = make_int2(e.x, __float_as_int(w));
    }
}

// ---- prep: feat fp32->bf16 cast + weight transpose/convert ----
__global__ void prep_kernel(const float* __restrict__ feat, unsigned* __restrict__ xb,
                            const float* __restrict__ W1, const float* __restrict__ W2,
                            unsigned short* __restrict__ W1T, unsigned short* __restrict__ W2T,
                            int nfeat2) {
    int i = blockIdx.x * blockDim.x + threadIdx.x;
    if (i < nfeat2) {
        float2 f = *(const float2*)(feat + (size_t)i * 2);
        xb[i] = pack_bf16x2(f.x, f.y);
        return;
    }
    int j = i - nfeat2;
    if (j < 256 * 128) {                       // W1T[n][k] = W1[k][n]
        int n = j >> 7, k = j & 127;
        W1T[j] = f2bf(W1[k * 256 + n]);
        return;
    }
    int k2 = j - 256 * 128;
    if (k2 < 48 * 256) {                       // W2T[c][k] = W2[k][c], pad c to 48
        int c = k2 >> 8, kk = k2 & 255;
        W2T[k2] = (c < 40) ? f2bf(W2[kk * 40 + c]) : (unsigned short)0;
    }
}

// ---- propagation (steps 1,2): wave per node, quarter-wave dwordx4 gathers ----
__global__ __launch_bounds__(256) void prop_kernel(
        const unsigned* __restrict__ xin, unsigned* __restrict__ xout,
        const int* __restrict__ offs, const int2* __restrict__ csr, int N) {
    int t = threadIdx.x;
    int wv = t >> 6, lane = t & 63;
    int q = lane >> 4, ql = lane & 15;
    int v = blockIdx.x * 4 + wv;
    if (v >= N) return;
    __shared__ int2 sIW[4][64];
    int start = offs[v], end = offs[v + 1];
    float a0 = 0.f, a1 = 0.f, a2 = 0.f, a3 = 0.f;
    float a4 = 0.f, a5 = 0.f, a6 = 0.f, a7 = 0.f;
    for (int k = start; k < end; k += 64) {
        int cnt = min(64, end - k);
        if (lane < cnt) sIW[wv][lane] = csr[k + lane];   // same-wave LDS: ordered
        int j = 0;
        for (; j + 16 <= cnt; j += 16) {
            uint4 d[4]; float w[4];
#pragma unroll
            for (int u = 0; u < 4; ++u) {
                int2 e = sIW[wv][j + 4 * u + q];
                w[u] = __int_as_float(e.y);
                d[u] = *(const uint4*)(xin + (size_t)e.x * 64 + ql * 4);
            }
#pragma unroll
            for (int u = 0; u < 4; ++u) {
                a0 += lo16(d[u].x) * w[u]; a1 += hi16(d[u].x) * w[u];
                a2 += lo16(d[u].y) * w[u]; a3 += hi16(d[u].y) * w[u];
                a4 += lo16(d[u].z) * w[u]; a5 += hi16(d[u].z) * w[u];
                a6 += lo16(d[u].w) * w[u]; a7 += hi16(d[u].w) * w[u];
            }
        }
        for (; j < cnt; j += 4) {
            int idx = j + q;
            float w = 0.f; uint4 d = make_uint4(0u, 0u, 0u, 0u);
            if (idx < cnt) {
                int2 e = sIW[wv][idx];
                w = __int_as_float(e.y);
                d = *(const uint4*)(xin + (size_t)e.x * 64 + ql * 4);
            }
            a0 += lo16(d.x) * w; a1 += hi16(d.x) * w;
            a2 += lo16(d.y) * w; a3 += hi16(d.y) * w;
            a4 += lo16(d.z) * w; a5 += hi16(d.z) * w;
            a6 += lo16(d.w) * w; a7 += hi16(d.w) * w;
        }
    }
    a0 += __shfl_xor(a0, 16, 64); a0 += __shfl_xor(a0, 32, 64);
    a1 += __shfl_xor(a1, 16, 64); a1 += __shfl_xor(a1, 32, 64);
    a2 += __shfl_xor(a2, 16, 64); a2 += __shfl_xor(a2, 32, 64);
    a3 += __shfl_xor(a3, 16, 64); a3 += __shfl_xor(a3, 32, 64);
    a4 += __shfl_xor(a4, 16, 64); a4 += __shfl_xor(a4, 32, 64);
    a5 += __shfl_xor(a5, 16, 64); a5 += __shfl_xor(a5, 32, 64);
    a6 += __shfl_xor(a6, 16, 64); a6 += __shfl_xor(a6, 32, 64);
    a7 += __shfl_xor(a7, 16, 64); a7 += __shfl_xor(a7, 32, 64);
    if (q == 0) {
        uint4 o;
        o.x = pack_bf16x2(a0, a1); o.y = pack_bf16x2(a2, a3);
        o.z = pack_bf16x2(a4, a5); o.w = pack_bf16x2(a6, a7);
        *(uint4*)(xout + (size_t)v * 64 + ql * 4) = o;
    }
}

// ---- prop step 3 + final average: ysum = (feat + x1 + x2 + x3) * 0.25 (bf16) ----
__global__ __launch_bounds__(256) void prop3_sum_kernel(
        const unsigned* __restrict__ x2, const float* __restrict__ feat,
        const unsigned* __restrict__ x1, unsigned* __restrict__ ysum,
        const int* __restrict__ offs, const int2* __restrict__ csr, int N) {
    int t = threadIdx.x;
    int wv = t >> 6, lane = t & 63;
    int q = lane >> 4, ql = lane & 15;
    int v = blockIdx.x * 4 + wv;
    if (v >= N) return;
    __shared__ int2 sIW[4][64];
    int start = offs[v], end = offs[v + 1];
    float a0 = 0.f, a1 = 0.f, a2 = 0.f, a3 = 0.f;
    float a4 = 0.f, a5 = 0.f, a6 = 0.f, a7 = 0.f;
    for (int k = start; k < end; k += 64) {
        int cnt = min(64, end - k);
        if (lane < cnt) sIW[wv][lane] = csr[k + lane];
        int j = 0;
        for (; j + 16 <= cnt; j += 16) {
            uint4 d[4]; float w[4];
#pragma unroll
            for (int u = 0; u < 4; ++u) {
                int2 e = sIW[wv][j + 4 * u + q];
                w[u] = __int_as_float(e.y);
                d[u] = *(const uint4*)(x2 + (size_t)e.x * 64 + ql * 4);
            }
#pragma unroll
            for (int u = 0; u < 4; ++u) {
                a0 += lo16(d[u].x) * w[u]; a1 += hi16(d[u].x) * w[u];
                a2 += lo16(d[u].y) * w[u]; a3 += hi16(d[u].y) * w[u];
                a4 += lo16(d[u].z) * w[u]; a5 += hi16(d[u].z) * w[u];
                a6 += lo16(d[u].w) * w[u]; a7 += hi16(d[u].w) * w[u];
            }
        }
        for (; j < cnt; j += 4) {
            int idx = j + q;
            float w = 0.f; uint4 d = make_uint4(0u, 0u, 0u, 0u);
            if (idx < cnt) {
                int2 e = sIW[wv][idx];
                w = __int_as_float(e.y);
                d = *(const uint4*)(x2 + (size_t)e.x * 64 + ql * 4);
            }
            a0 += lo16(d.x) * w; a1 += hi16(d.x) * w;
            a2 += lo16(d.y) * w; a3 += hi16(d.y) * w;
            a4 += lo16(d.z) * w; a5 += hi16(d.z) * w;
            a6 += lo16(d.w) * w; a7 += hi16(d.w) * w;
        }
    }
    a0 += __shfl_xor(a0, 16, 64); a0 += __shfl_xor(a0, 32, 64);
    a1 += __shfl_xor(a1, 16, 64); a1 += __shfl_xor(a1, 32, 64);
    a2 += __shfl_xor(a2, 16, 64); a2 += __shfl_xor(a2, 32, 64);
    a3 += __shfl_xor(a3, 16, 64); a3 += __shfl_xor(a3, 32, 64);
    a4 += __shfl_xor(a4, 16, 64); a4 += __shfl_xor(a4, 32, 64);
    a5 += __shfl_xor(a5, 16, 64); a5 += __shfl_xor(a5, 32, 64);
    a6 += __shfl_xor(a6, 16, 64); a6 += __shfl_xor(a6, 32, 64);
    a7 += __shfl_xor(a7, 16, 64); a7 += __shfl_xor(a7, 32, 64);
    if (q == 0) {
        size_t fo = (size_t)v * 128 + ql * 8;
        float4 f0 = *(const float4*)(feat + fo);
        float4 f1 = *(const float4*)(feat + fo + 4);
        uint4 u1 = *(const uint4*)(x1 + (size_t)v * 64 + ql * 4);
        uint4 u2 = *(const uint4*)(x2 + (size_t)v * 64 + ql * 4);
        float s0 = (f0.x + lo16(u1.x) + lo16(u2.x) + a0) * 0.25f;
        float s1 = (f0.y + hi16(u1.x) + hi16(u2.x) + a1) * 0.25f;
        float s2 = (f0.z + lo16(u1.y) + lo16(u2.y) + a2) * 0.25f;
        float s3 = (f0.w + hi16(u1.y) + hi16(u2.y) + a3) * 0.25f;
        float s4 = (f1.x + lo16(u1.z) + lo16(u2.z) + a4) * 0.25f;
        float s5 = (f1.y + hi16(u1.z) + hi16(u2.z) + a5) * 0.25f;
        float s6 = (f1.z + lo16(u1.w) + lo16(u2.w) + a6) * 0.25f;
        float s7 = (f1.w + hi16(u1.w) + hi16(u2.w) + a7) * 0.25f;
        uint4 o;
        o.x = pack_bf16x2(s0, s1); o.y = pack_bf16x2(s2, s3);
        o.z = pack_bf16x2(s4, s5); o.w = pack_bf16x2(s6, s7);
        *(uint4*)(ysum + (size_t)v * 64 + ql * 4) = o;
    }
}

// ---- MLP on 16-node tiles: high block count, small LDS ----
typedef __attribute__((ext_vector_type(8))) short bf16x8;
typedef __attribute__((ext_vector_type(4))) float f32x4;

#define SA_STRIDE 136   // 128 + 8 bf16 pad (row = 17*16B)
#define SH_STRIDE 264   // 256 + 8 bf16 pad (row = 33*16B)

__global__ __launch_bounds__(256) void mlp16_kernel(
        const unsigned* __restrict__ ysum,
        const unsigned short* __restrict__ W1T, const float* __restrict__ b1,
        const unsigned short* __restrict__ W2T, const float* __restrict__ b2,
        float* __restrict__ out, int N) {
    __shared__ unsigned short sA[16 * SA_STRIDE];
    __shared__ unsigned short sH[16 * SH_STRIDE];
    int t = threadIdx.x, wv = t >> 6, lane = t & 63;
    int l15 = lane & 15, lq = lane >> 4;
    int base = blockIdx.x * 16;

    // stage A: one uint4 (8 bf16) per thread: 16 nodes x 128 k
    {
        int n = t >> 4, sg = t & 15;
        int gv = base + n;
        uint4 u = make_uint4(0u, 0u, 0u, 0u);
        if (gv < N) u = *(const uint4*)(ysum + (size_t)gv * 64 + sg * 4);
        *(uint4*)&sA[n * SA_STRIDE + sg * 8] = u;
    }
    __syncthreads();

    // matmul1: wave wv -> hid [wv*64, +64) for 16 nodes
    f32x4 acc[4];
#pragma unroll
    for (int ht = 0; ht < 4; ++ht) acc[ht] = (f32x4){0.f, 0.f, 0.f, 0.f};
#pragma unroll
    for (int s = 0; s < 4; ++s) {
        bf16x8 afr = *(const bf16x8*)&sA[l15 * SA_STRIDE + s * 32 + lq * 8];
#pragma unroll
        for (int ht = 0; ht < 4; ++ht) {
            bf16x8 bfr = *(const bf16x8*)(W1T + ((wv * 64 + ht * 16 + l15) * 128 + s * 32 + lq * 8));
            acc[ht] = __builtin_amdgcn_mfma_f32_16x16x32_bf16(afr, bfr, acc[ht], 0, 0, 0);
        }
    }
#pragma unroll
    for (int ht = 0; ht < 4; ++ht) {
        int hid = wv * 64 + ht * 16 + l15;
        float bb = b1[hid];
#pragma unroll
        for (int r = 0; r < 4; ++r) {
            int node = lq * 4 + r;
            sH[node * SH_STRIDE + hid] = f2bf(fmaxf(acc[ht][r] + bb, 0.f));
        }
    }
    __syncthreads();
    if (wv != 0) return;

    // wave 0: matmul2 (16 nodes x 48 classes, K=256) + log_softmax
    f32x4 acc2[3];
#pragma unroll
    for (int ct = 0; ct < 3; ++ct) acc2[ct] = (f32x4){0.f, 0.f, 0.f, 0.f};
#pragma unroll
    for (int s = 0; s < 8; ++s) {
        bf16x8 afr = *(const bf16x8*)&sH[l15 * SH_STRIDE + s * 32 + lq * 8];
#pragma unroll
        for (int ct = 0; ct < 3; ++ct) {
            bf16x8 bfr = *(const bf16x8*)(W2T + ((ct * 16 + l15) * 256 + s * 32 + lq * 8));
            acc2[ct] = __builtin_amdgcn_mfma_f32_16x16x32_bf16(afr, bfr, acc2[ct], 0, 0, 0);
        }
    }

    float lg[3][4];
#pragma unroll
    for (int ct = 0; ct < 3; ++ct) {
        int c = ct * 16 + l15;
        float bb = (c < NCLS) ? b2[c] : 0.f;
#pragma unroll
        for (int r = 0; r < 4; ++r) lg[ct][r] = acc2[ct][r] + bb;
    }
#pragma unroll
    for (int r = 0; r < 4; ++r) {
        float m = fmaxf(lg[0][r], lg[1][r]);
        if (l15 < 8) m = fmaxf(m, lg[2][r]);
        for (int off = 1; off < 16; off <<= 1) m = fmaxf(m, __shfl_xor(m, off, 64));
        float ssum = __expf(lg[0][r] - m) + __expf(lg[1][r] - m) +
                     ((l15 < 8) ? __expf(lg[2][r] - m) : 0.f);
        for (int off = 1; off < 16; off <<= 1) ssum += __shfl_xor(ssum, off, 64);
        float ls = m + __logf(ssum);
        int node = base + lq * 4 + r;
        if (node < N) {
#pragma unroll
            for (int ct = 0; ct < 3; ++ct) {
                int c = ct * 16 + l15;
                if (c < NCLS) out[(size_t)node * NCLS + c] = lg[ct][r] - ls;
            }
        }
    }
}

extern "C" void kernel_launch(void* const* d_in, const int* in_sizes, int n_in,
                              void* d_out, int out_size, void* d_ws, size_t ws_size,
                              hipStream_t stream) {
    const float* feat = (const float*)d_in[0];
    const int*   src  = (const int*)d_in[1];
    const int*   dst  = (const int*)d_in[2];
    const float* W1   = (const float*)d_in[3];
    const float* b1   = (const float*)d_in[4];
    const float* W2   = (const float*)d_in[5];
    const float* b2   = (const float*)d_in[6];
    float* out = (float*)d_out;

    int N = in_sizes[0] / IN_DIM;
    int E = in_sizes[1];
    int NB = (N + BSZ - 1) / BSZ;

    char* ws = (char*)d_ws;
    size_t off = 0;
    float* norm   = (float*)(ws + off); off += align256((size_t)N * 4);
    int*   offs   = (int*)(ws + off);   off += align256((size_t)(N + 1) * 4);
    int*   bBase  = (int*)(ws + off);   off += align256((size_t)(MAXNB + 1) * 4);
    int*   bCur   = (int*)(ws + off);   off += align256((size_t)MAXNB * 4);
    int*   bCnt   = (int*)(ws + off);   off += align256((size_t)MAXNB * 4);
    int2*  csr    = (int2*)(ws + off);  off += align256((size_t)E * 8);
    unsigned* x0  = (unsigned*)(ws + off); off += align256((size_t)N * 64 * 4);
    unsigned* x1  = (unsigned*)(ws + off); off += align256((size_t)N * 64 * 4);
    unsigned* x2  = (unsigned*)(ws + off); off += align256((size_t)N * 64 * 4);
    unsigned short* W1T = (unsigned short*)(ws + off); off += align256((size_t)256 * 128 * 2);
    unsigned short* W2T = (unsigned short*)(ws + off); off += align256((size_t)48 * 256 * 2);
    (void)ws_size;
    int2* ebuf = (int2*)x1;        // alias: ebuf dead before prop1 writes x1
    unsigned* ysum = x0;           // alias: x0 dead after prop1

    hipMemsetAsync(bCnt, 0, (size_t)MAXNB * 4, stream);

    int echunks = (E + CHUNK - 1) / CHUNK;
    bucket_count_kernel<<<echunks, 256, 0, stream>>>(dst, bCnt, E, NB);
    bucket_scan_kernel<<<1, 256, 0, stream>>>(bCnt, bBase, bCur, offs, NB, N);
    bucket_scatter_kernel<<<echunks, 256, 0, stream>>>(src, dst, bCur, ebuf, E);
    build_norm_kernel<<<NB, 256, 0, stream>>>(ebuf, bBase, offs, norm, N);
    build_csr_kernel<<<NB, 256, 0, stream>>>(ebuf, bBase, offs, norm, csr, N);

    int nprep = N * 64 + 256 * 128 + 48 * 256;
    prep_kernel<<<(nprep + 255) / 256, 256, 0, stream>>>(feat, x0, W1, W2, W1T, W2T, N * 64);

    int pb = (N + 3) / 4;
    prop_kernel<<<pb, 256, 0, stream>>>(x0, x1, offs, csr, N);
    prop_kernel<<<pb, 256, 0, stream>>>(x1, x2, offs, csr, N);
    prop3_sum_kernel<<<pb, 256, 0, stream>>>(x2, feat, x1, ysum, offs, csr, N);

    mlp16_kernel<<<(N + 15) / 16, 256, 0, stream>>>(ysum, W1T, b1, W2T, b2, out, N);
}

// Round 8
// 257.003 us; speedup vs baseline: 1.1044x; 1.0199x over previous
//
#include <hip/hip_runtime.h>

#define IN_DIM 128
#define HID    256
#define NCLS   40
#define BSHIFT 8
#define BSZ    256     // nodes per bucket
#define MAXNB  256     // max buckets (N <= 65536)
#define CHUNK  4096    // edges per scatter block

static inline size_t align256(size_t x) { return (x + 255) & ~(size_t)255; }

__device__ inline unsigned pack_bf16x2(float x, float y) {
    unsigned xb = __float_as_uint(x), yb = __float_as_uint(y);
    unsigned lo = (xb + 0x7fffu + ((xb >> 16) & 1u)) >> 16;
    unsigned hi = (yb + 0x7fffu + ((yb >> 16) & 1u)) >> 16;
    return lo | (hi << 16);
}
__device__ inline unsigned short f2bf(float x) {
    unsigned b = __float_as_uint(x);
    return (unsigned short)((b + 0x7fffu + ((b >> 16) & 1u)) >> 16);
}
__device__ inline float lo16(unsigned u) { return __uint_as_float(u << 16); }
__device__ inline float hi16(unsigned u) { return __uint_as_float(u & 0xffff0000u); }

// ---- K1: bucket histogram ----
__global__ __launch_bounds__(256) void bucket_count_kernel(
        const int* __restrict__ dst, int* __restrict__ bucketCnt, int E, int NB) {
    __shared__ int hist[MAXNB];
    int t = threadIdx.x;
    hist[t] = 0;
    __syncthreads();
    int start = blockIdx.x * CHUNK;
    int cnt = min(CHUNK, E - start);
    for (int i = t; i < cnt; i += 256) atomicAdd(&hist[dst[start + i] >> BSHIFT], 1);
    __syncthreads();
    if (t < NB && hist[t]) atomicAdd(&bucketCnt[t], hist[t]);
}

// ---- K2: scan bucket totals ----
__global__ __launch_bounds__(256) void bucket_scan_kernel(
        const int* __restrict__ bucketCnt, int* __restrict__ bucketBase,
        int* __restrict__ bucketCursor, int* __restrict__ offs, int NB, int N) {
    int t = threadIdx.x, lane = t & 63, wave = t >> 6;
    int v = (t < NB) ? bucketCnt[t] : 0;
    int s = v;
    for (int off = 1; off < 64; off <<= 1) {
        int u = __shfl_up(s, off, 64);
        if (lane >= off) s += u;
    }
    __shared__ int wsum[4];
    if (lane == 63) wsum[wave] = s;
    __syncthreads();
    if (t == 0) {
        int c = 0;
        for (int i = 0; i < 4; ++i) { int x = wsum[i]; wsum[i] = c; c += x; }
    }
    __syncthreads();
    int incl = wsum[wave] + s;
    int excl = incl - v;
    if (t < NB) { bucketBase[t] = excl; bucketCursor[t] = excl; }
    if (t == NB - 1) { bucketBase[NB] = incl; offs[N] = incl; }
}

// ---- K3: bucket-ordered scatter via LDS binning ----
__global__ __launch_bounds__(256) void bucket_scatter_kernel(
        const int* __restrict__ src, const int* __restrict__ dst,
        int* __restrict__ bucketCursor, int2* __restrict__ ebuf, int E) {
    __shared__ int hist[MAXNB], lofs[MAXNB], lcur[MAXNB], gbase[MAXNB];
    __shared__ int2 bin[CHUNK];
    int t = threadIdx.x, lane = t & 63, wave = t >> 6;
    int start = blockIdx.x * CHUNK;
    int cnt = min(CHUNK, E - start);
    hist[t] = 0;
    __syncthreads();
    for (int i = t; i < cnt; i += 256) atomicAdd(&hist[dst[start + i] >> BSHIFT], 1);
    __syncthreads();
    int v = hist[t];
    int s = v;
    for (int off = 1; off < 64; off <<= 1) {
        int u = __shfl_up(s, off, 64);
        if (lane >= off) s += u;
    }
    __shared__ int wsum[4];
    if (lane == 63) wsum[wave] = s;
    __syncthreads();
    if (t == 0) {
        int c = 0;
        for (int i = 0; i < 4; ++i) { int x = wsum[i]; wsum[i] = c; c += x; }
    }
    __syncthreads();
    int excl = wsum[wave] + s - v;
    lofs[t] = excl; lcur[t] = excl;
    if (v) gbase[t] = atomicAdd(&bucketCursor[t], v);
    __syncthreads();
    for (int i = t; i < cnt; i += 256) {
        int s0 = src[start + i], d0 = dst[start + i];
        int r = atomicAdd(&lcur[d0 >> BSHIFT], 1);
        bin[r] = make_int2(s0, d0);
    }
    __syncthreads();
    for (int i = t; i < cnt; i += 256) {
        int2 e = bin[i];
        int b = e.y >> BSHIFT;
        ebuf[gbase[b] + i - lofs[b]] = e;
    }
}

// ---- K4: per-bucket degrees -> offs, norm ----
__global__ __launch_bounds__(256) void build_norm_kernel(
        const int2* __restrict__ ebuf, const int* __restrict__ bucketBase,
        int* __restrict__ offs, float* __restrict__ norm, int N) {
    __shared__ int hist[BSZ];
    int b = blockIdx.x, t = threadIdx.x, lane = t & 63, wave = t >> 6;
    hist[t] = 0;
    __syncthreads();
    int segS = bucketBase[b], segE = bucketBase[b + 1];
    for (int i = segS + t; i < segE; i += 256) atomicAdd(&hist[ebuf[i].y & (BSZ - 1)], 1);
    __syncthreads();
    int v = hist[t];
    int s = v;
    for (int off = 1; off < 64; off <<= 1) {
        int u = __shfl_up(s, off, 64);
        if (lane >= off) s += u;
    }
    __shared__ int wsum[4];
    if (lane == 63) wsum[wave] = s;
    __syncthreads();
    if (t == 0) {
        int c = 0;
        for (int i = 0; i < 4; ++i) { int x = wsum[i]; wsum[i] = c; c += x; }
    }
    __syncthreads();
    int excl = wsum[wave] + s - v;
    int node = b * BSZ + t;
    if (node < N) {
        offs[node] = segS + excl;
        norm[node] = rsqrtf((float)(v > 0 ? v : 1));
    }
}

// ---- K5: per-bucket exact CSR placement with weights ----
__global__ __launch_bounds__(256) void build_csr_kernel(
        const int2* __restrict__ ebuf, const int* __restrict__ bucketBase,
        const int* __restrict__ offs, const float* __restrict__ norm,
        int2* __restrict__ csr, int N) {
    __shared__ int lcur[BSZ];
    __shared__ float snorm[BSZ];
    int b = blockIdx.x, t = threadIdx.x;
    int node = b * BSZ + t;
    lcur[t] = (node < N) ? offs[node] : 0;
    snorm[t] = (node < N) ? norm[node] : 0.f;
    __syncthreads();
    int segS = bucketBase[b], segE = bucketBase[b + 1];
    for (int i = segS + t; i < segE; i += 256) {
        int2 e = ebuf[i];
        int li = e.y & (BSZ - 1);
        float w = norm[e.x] * snorm[li];
        int p = atomicAdd(&lcur[li], 1);
        csr[p] = make_int2(e.x, __float_as_int(w));
    }
}

// ---- prep: feat fp32->bf16 cast + weight transpose/convert ----
__global__ void prep_kernel(const float* __restrict__ feat, unsigned* __restrict__ xb,
                            const float* __restrict__ W1, const float* __restrict__ W2,
                            unsigned short* __restrict__ W1T, unsigned short* __restrict__ W2T,
                            int nfeat2) {
    int i = blockIdx.x * blockDim.x + threadIdx.x;
    if (i < nfeat2) {
        float2 f = *(const float2*)(feat + (size_t)i * 2);
        xb[i] = pack_bf16x2(f.x, f.y);
        return;
    }
    int j = i - nfeat2;
    if (j < 256 * 128) {                       // W1T[n][k] = W1[k][n]
        int n = j >> 7, k = j & 127;
        W1T[j] = f2bf(W1[k * 256 + n]);
        return;
    }
    int k2 = j - 256 * 128;
    if (k2 < 48 * 256) {                       // W2T[c][k] = W2[k][c], pad c to 48
        int c = k2 >> 8, kk = k2 & 255;
        W2T[k2] = (c < 40) ? f2bf(W2[kk * 40 + c]) : (unsigned short)0;
    }
}

// ---- shared gather macro body: full 16-edge groups + one masked 16-edge group ----
// (4 uint4 loads in flight per quarter-wave for EVERY edge, tail included)

// ---- propagation (steps 1,2): wave per node ----
__global__ __launch_bounds__(256) void prop_kernel(
        const unsigned* __restrict__ xin, unsigned* __restrict__ xout,
        const int* __restrict__ offs, const int2* __restrict__ csr, int N) {
    int t = threadIdx.x;
    int wv = t >> 6, lane = t & 63;
    int q = lane >> 4, ql = lane & 15;
    int v = blockIdx.x * 4 + wv;
    if (v >= N) return;
    __shared__ int2 sIW[4][64];
    int start = offs[v], end = offs[v + 1];
    float a0 = 0.f, a1 = 0.f, a2 = 0.f, a3 = 0.f;
    float a4 = 0.f, a5 = 0.f, a6 = 0.f, a7 = 0.f;
    for (int k = start; k < end; k += 64) {
        int cnt = min(64, end - k);
        if (lane < cnt) sIW[wv][lane] = csr[k + lane];   // same-wave LDS: ordered
        int j = 0;
        for (; j + 16 <= cnt; j += 16) {
            uint4 d[4]; float w[4];
#pragma unroll
            for (int u = 0; u < 4; ++u) {
                int2 e = sIW[wv][j + 4 * u + q];
                w[u] = __int_as_float(e.y);
                d[u] = *(const uint4*)(xin + (size_t)e.x * 64 + ql * 4);
            }
#pragma unroll
            for (int u = 0; u < 4; ++u) {
                a0 += lo16(d[u].x) * w[u]; a1 += hi16(d[u].x) * w[u];
                a2 += lo16(d[u].y) * w[u]; a3 += hi16(d[u].y) * w[u];
                a4 += lo16(d[u].z) * w[u]; a5 += hi16(d[u].z) * w[u];
                a6 += lo16(d[u].w) * w[u]; a7 += hi16(d[u].w) * w[u];
            }
        }
        if (j < cnt) {                         // masked final group: still 4-deep
            uint4 d[4]; float w[4];
#pragma unroll
            for (int u = 0; u < 4; ++u) {
                int idx = j + 4 * u + q;
                int2 e = sIW[wv][min(idx, cnt - 1)];
                w[u] = (idx < cnt) ? __int_as_float(e.y) : 0.f;
                d[u] = *(const uint4*)(xin + (size_t)e.x * 64 + ql * 4);
            }
#pragma unroll
            for (int u = 0; u < 4; ++u) {
                a0 += lo16(d[u].x) * w[u]; a1 += hi16(d[u].x) * w[u];
                a2 += lo16(d[u].y) * w[u]; a3 += hi16(d[u].y) * w[u];
                a4 += lo16(d[u].z) * w[u]; a5 += hi16(d[u].z) * w[u];
                a6 += lo16(d[u].w) * w[u]; a7 += hi16(d[u].w) * w[u];
            }
        }
    }
    a0 += __shfl_xor(a0, 16, 64); a0 += __shfl_xor(a0, 32, 64);
    a1 += __shfl_xor(a1, 16, 64); a1 += __shfl_xor(a1, 32, 64);
    a2 += __shfl_xor(a2, 16, 64); a2 += __shfl_xor(a2, 32, 64);
    a3 += __shfl_xor(a3, 16, 64); a3 += __shfl_xor(a3, 32, 64);
    a4 += __shfl_xor(a4, 16, 64); a4 += __shfl_xor(a4, 32, 64);
    a5 += __shfl_xor(a5, 16, 64); a5 += __shfl_xor(a5, 32, 64);
    a6 += __shfl_xor(a6, 16, 64); a6 += __shfl_xor(a6, 32, 64);
    a7 += __shfl_xor(a7, 16, 64); a7 += __shfl_xor(a7, 32, 64);
    if (q == 0) {
        uint4 o;
        o.x = pack_bf16x2(a0, a1); o.y = pack_bf16x2(a2, a3);
        o.z = pack_bf16x2(a4, a5); o.w = pack_bf16x2(a6, a7);
        *(uint4*)(xout + (size_t)v * 64 + ql * 4) = o;
    }
}

// ---- prop step 3 + final average: ysum = (feat + x1 + x2 + x3) * 0.25 (bf16) ----
__global__ __launch_bounds__(256) void prop3_sum_kernel(
        const unsigned* __restrict__ x2, const float* __restrict__ feat,
        const unsigned* __restrict__ x1, unsigned* __restrict__ ysum,
        const int* __restrict__ offs, const int2* __restrict__ csr, int N) {
    int t = threadIdx.x;
    int wv = t >> 6, lane = t & 63;
    int q = lane >> 4, ql = lane & 15;
    int v = blockIdx.x * 4 + wv;
    if (v >= N) return;
    __shared__ int2 sIW[4][64];
    int start = offs[v], end = offs[v + 1];
    float a0 = 0.f, a1 = 0.f, a2 = 0.f, a3 = 0.f;
    float a4 = 0.f, a5 = 0.f, a6 = 0.f, a7 = 0.f;
    for (int k = start; k < end; k += 64) {
        int cnt = min(64, end - k);
        if (lane < cnt) sIW[wv][lane] = csr[k + lane];
        int j = 0;
        for (; j + 16 <= cnt; j += 16) {
            uint4 d[4]; float w[4];
#pragma unroll
            for (int u = 0; u < 4; ++u) {
                int2 e = sIW[wv][j + 4 * u + q];
                w[u] = __int_as_float(e.y);
                d[u] = *(const uint4*)(x2 + (size_t)e.x * 64 + ql * 4);
            }
#pragma unroll
            for (int u = 0; u < 4; ++u) {
                a0 += lo16(d[u].x) * w[u]; a1 += hi16(d[u].x) * w[u];
                a2 += lo16(d[u].y) * w[u]; a3 += hi16(d[u].y) * w[u];
                a4 += lo16(d[u].z) * w[u]; a5 += hi16(d[u].z) * w[u];
                a6 += lo16(d[u].w) * w[u]; a7 += hi16(d[u].w) * w[u];
            }
        }
        if (j < cnt) {
            uint4 d[4]; float w[4];
#pragma unroll
            for (int u = 0; u < 4; ++u) {
                int idx = j + 4 * u + q;
                int2 e = sIW[wv][min(idx, cnt - 1)];
                w[u] = (idx < cnt) ? __int_as_float(e.y) : 0.f;
                d[u] = *(const uint4*)(x2 + (size_t)e.x * 64 + ql * 4);
            }
#pragma unroll
            for (int u = 0; u < 4; ++u) {
                a0 += lo16(d[u].x) * w[u]; a1 += hi16(d[u].x) * w[u];
                a2 += lo16(d[u].y) * w[u]; a3 += hi16(d[u].y) * w[u];
                a4 += lo16(d[u].z) * w[u]; a5 += hi16(d[u].z) * w[u];
                a6 += lo16(d[u].w) * w[u]; a7 += hi16(d[u].w) * w[u];
            }
        }
    }
    a0 += __shfl_xor(a0, 16, 64); a0 += __shfl_xor(a0, 32, 64);
    a1 += __shfl_xor(a1, 16, 64); a1 += __shfl_xor(a1, 32, 64);
    a2 += __shfl_xor(a2, 16, 64); a2 += __shfl_xor(a2, 32, 64);
    a3 += __shfl_xor(a3, 16, 64); a3 += __shfl_xor(a3, 32, 64);
    a4 += __shfl_xor(a4, 16, 64); a4 += __shfl_xor(a4, 32, 64);
    a5 += __shfl_xor(a5, 16, 64); a5 += __shfl_xor(a5, 32, 64);
    a6 += __shfl_xor(a6, 16, 64); a6 += __shfl_xor(a6, 32, 64);
    a7 += __shfl_xor(a7, 16, 64); a7 += __shfl_xor(a7, 32, 64);
    if (q == 0) {
        size_t fo = (size_t)v * 128 + ql * 8;
        float4 f0 = *(const float4*)(feat + fo);
        float4 f1 = *(const float4*)(feat + fo + 4);
        uint4 u1 = *(const uint4*)(x1 + (size_t)v * 64 + ql * 4);
        uint4 u2 = *(const uint4*)(x2 + (size_t)v * 64 + ql * 4);
        float s0 = (f0.x + lo16(u1.x) + lo16(u2.x) + a0) * 0.25f;
        float s1 = (f0.y + hi16(u1.x) + hi16(u2.x) + a1) * 0.25f;
        float s2 = (f0.z + lo16(u1.y) + lo16(u2.y) + a2) * 0.25f;
        float s3 = (f0.w + hi16(u1.y) + hi16(u2.y) + a3) * 0.25f;
        float s4 = (f1.x + lo16(u1.z) + lo16(u2.z) + a4) * 0.25f;
        float s5 = (f1.y + hi16(u1.z) + hi16(u2.z) + a5) * 0.25f;
        float s6 = (f1.z + lo16(u1.w) + lo16(u2.w) + a6) * 0.25f;
        float s7 = (f1.w + hi16(u1.w) + hi16(u2.w) + a7) * 0.25f;
        uint4 o;
        o.x = pack_bf16x2(s0, s1); o.y = pack_bf16x2(s2, s3);
        o.z = pack_bf16x2(s4, s5); o.w = pack_bf16x2(s6, s7);
        *(uint4*)(ysum + (size_t)v * 64 + ql * 4) = o;
    }
}

// ---- MLP on 16-node tiles ----
typedef __attribute__((ext_vector_type(8))) short bf16x8;
typedef __attribute__((ext_vector_type(4))) float f32x4;

#define SA_STRIDE 136   // 128 + 8 bf16 pad
#define SH_STRIDE 264   // 256 + 8 bf16 pad

__global__ __launch_bounds__(256) void mlp16_kernel(
        const unsigned* __restrict__ ysum,
        const unsigned short* __restrict__ W1T, const float* __restrict__ b1,
        const unsigned short* __restrict__ W2T, const float* __restrict__ b2,
        float* __restrict__ out, int N) {
    __shared__ unsigned short sA[16 * SA_STRIDE];
    __shared__ unsigned short sH[16 * SH_STRIDE];
    int t = threadIdx.x, wv = t >> 6, lane = t & 63;
    int l15 = lane & 15, lq = lane >> 4;
    int base = blockIdx.x * 16;

    {
        int n = t >> 4, sg = t & 15;
        int gv = base + n;
        uint4 u = make_uint4(0u, 0u, 0u, 0u);
        if (gv < N) u = *(const uint4*)(ysum + (size_t)gv * 64 + sg * 4);
        *(uint4*)&sA[n * SA_STRIDE + sg * 8] = u;
    }
    __syncthreads();

    f32x4 acc[4];
#pragma unroll
    for (int ht = 0; ht < 4; ++ht) acc[ht] = (f32x4){0.f, 0.f, 0.f, 0.f};
#pragma unroll
    for (int s = 0; s < 4; ++s) {
        bf16x8 afr = *(const bf16x8*)&sA[l15 * SA_STRIDE + s * 32 + lq * 8];
#pragma unroll
        for (int ht = 0; ht < 4; ++ht) {
            bf16x8 bfr = *(const bf16x8*)(W1T + ((wv * 64 + ht * 16 + l15) * 128 + s * 32 + lq * 8));
            acc[ht] = __builtin_amdgcn_mfma_f32_16x16x32_bf16(afr, bfr, acc[ht], 0, 0, 0);
        }
    }
#pragma unroll
    for (int ht = 0; ht < 4; ++ht) {
        int hid = wv * 64 + ht * 16 + l15;
        float bb = b1[hid];
#pragma unroll
        for (int r = 0; r < 4; ++r) {
            int node = lq * 4 + r;
            sH[node * SH_STRIDE + hid] = f2bf(fmaxf(acc[ht][r] + bb, 0.f));
        }
    }
    __syncthreads();
    if (wv != 0) return;

    f32x4 acc2[3];
#pragma unroll
    for (int ct = 0; ct < 3; ++ct) acc2[ct] = (f32x4){0.f, 0.f, 0.f, 0.f};
#pragma unroll
    for (int s = 0; s < 8; ++s) {
        bf16x8 afr = *(const bf16x8*)&sH[l15 * SH_STRIDE + s * 32 + lq * 8];
#pragma unroll
        for (int ct = 0; ct < 3; ++ct) {
            bf16x8 bfr = *(const bf16x8*)(W2T + ((ct * 16 + l15) * 256 + s * 32 + lq * 8));
            acc2[ct] = __builtin_amdgcn_mfma_f32_16x16x32_bf16(afr, bfr, acc2[ct], 0, 0, 0);
        }
    }

    float lg[3][4];
#pragma unroll
    for (int ct = 0; ct < 3; ++ct) {
        int c = ct * 16 + l15;
        float bb = (c < NCLS) ? b2[c] : 0.f;
#pragma unroll
        for (int r = 0; r < 4; ++r) lg[ct][r] = acc2[ct][r] + bb;
    }
#pragma unroll
    for (int r = 0; r < 4; ++r) {
        float m = fmaxf(lg[0][r], lg[1][r]);
        if (l15 < 8) m = fmaxf(m, lg[2][r]);
        for (int off = 1; off < 16; off <<= 1) m = fmaxf(m, __shfl_xor(m, off, 64));
        float ssum = __expf(lg[0][r] - m) + __expf(lg[1][r] - m) +
                     ((l15 < 8) ? __expf(lg[2][r] - m) : 0.f);
        for (int off = 1; off < 16; off <<= 1) ssum += __shfl_xor(ssum, off, 64);
        float ls = m + __logf(ssum);
        int node = base + lq * 4 + r;
        if (node < N) {
#pragma unroll
            for (int ct = 0; ct < 3; ++ct) {
                int c = ct * 16 + l15;
                if (c < NCLS) out[(size_t)node * NCLS + c] = lg[ct][r] - ls;
            }
        }
    }
}

extern "C" void kernel_launch(void* const* d_in, const int* in_sizes, int n_in,
                              void* d_out, int out_size, void* d_ws, size_t ws_size,
                              hipStream_t stream) {
    const float* feat = (const float*)d_in[0];
    const int*   src  = (const int*)d_in[1];
    const int*   dst  = (const int*)d_in[2];
    const float* W1   = (const float*)d_in[3];
    const float* b1   = (const float*)d_in[4];
    const float* W2   = (const float*)d_in[5];
    const float* b2   = (const float*)d_in[6];
    float* out = (float*)d_out;

    int N = in_sizes[0] / IN_DIM;
    int E = in_sizes[1];
    int NB = (N + BSZ - 1) / BSZ;

    char* ws = (char*)d_ws;
    size_t off = 0;
    float* norm   = (float*)(ws + off); off += align256((size_t)N * 4);
    int*   offs   = (int*)(ws + off);   off += align256((size_t)(N + 1) * 4);
    int*   bBase  = (int*)(ws + off);   off += align256((size_t)(MAXNB + 1) * 4);
    int*   bCur   = (int*)(ws + off);   off += align256((size_t)MAXNB * 4);
    int*   bCnt   = (int*)(ws + off);   off += align256((size_t)MAXNB * 4);
    int2*  csr    = (int2*)(ws + off);  off += align256((size_t)E * 8);
    unsigned* x0  = (unsigned*)(ws + off); off += align256((size_t)N * 64 * 4);
    unsigned* x1  = (unsigned*)(ws + off); off += align256((size_t)N * 64 * 4);
    unsigned* x2  = (unsigned*)(ws + off); off += align256((size_t)N * 64 * 4);
    unsigned short* W1T = (unsigned short*)(ws + off); off += align256((size_t)256 * 128 * 2);
    unsigned short* W2T = (unsigned short*)(ws + off); off += align256((size_t)48 * 256 * 2);
    (void)ws_size;
    int2* ebuf = (int2*)x1;        // alias: ebuf dead before prop1 writes x1
    unsigned* ysum = x0;           // alias: x0 dead after prop1

    hipMemsetAsync(bCnt, 0, (size_t)MAXNB * 4, stream);

    int echunks = (E + CHUNK - 1) / CHUNK;
    bucket_count_kernel<<<echunks, 256, 0, stream>>>(dst, bCnt, E, NB);
    bucket_scan_kernel<<<1, 256, 0, stream>>>(bCnt, bBase, bCur, offs, NB, N);
    bucket_scatter_kernel<<<echunks, 256, 0, stream>>>(src, dst, bCur, ebuf, E);
    build_norm_kernel<<<NB, 256, 0, stream>>>(ebuf, bBase, offs, norm, N);
    build_csr_kernel<<<NB, 256, 0, stream>>>(ebuf, bBase, offs, norm, csr, N);

    int nprep = N * 64 + 256 * 128 + 48 * 256;
    prep_kernel<<<(nprep + 255) / 256, 256, 0, stream>>>(feat, x0, W1, W2, W1T, W2T, N * 64);

    int pb = (N + 3) / 4;
    prop_kernel<<<pb, 256, 0, stream>>>(x0, x1, offs, csr, N);
    prop_kernel<<<pb, 256, 0, stream>>>(x1, x2, offs, csr, N);
    prop3_sum_kernel<<<pb, 256, 0, stream>>>(x2, feat, x1, ysum, offs, csr, N);

    mlp16_kernel<<<(N + 15) / 16, 256, 0, stream>>>(ysum, W1T, b1, W2T, b2, out, N);
}

// Round 9
// 226.785 us; speedup vs baseline: 1.2516x; 1.1332x over previous
//
#include <hip/hip_runtime.h>

#define IN_DIM 128
#define HID    256
#define NCLS   40
#define BSHIFT 8
#define BSZ    256     // nodes per bucket
#define MAXNB  256     // max buckets (N <= 65536)
#define CHUNK  4096    // edges per scatter block

static inline size_t align256(size_t x) { return (x + 255) & ~(size_t)255; }

typedef __attribute__((ext_vector_type(2))) float f32x2;

__device__ inline unsigned pack_bf16x2(float x, float y) {
    unsigned xb = __float_as_uint(x), yb = __float_as_uint(y);
    unsigned lo = (xb + 0x7fffu + ((xb >> 16) & 1u)) >> 16;
    unsigned hi = (yb + 0x7fffu + ((yb >> 16) & 1u)) >> 16;
    return lo | (hi << 16);
}
__device__ inline unsigned short f2bf(float x) {
    unsigned b = __float_as_uint(x);
    return (unsigned short)((b + 0x7fffu + ((b >> 16) & 1u)) >> 16);
}
__device__ inline float lo16(unsigned u) { return __uint_as_float(u << 16); }
__device__ inline float hi16(unsigned u) { return __uint_as_float(u & 0xffff0000u); }

// fp8 e4m3 (OCP on gfx950) pack/unpack via HW converts
__device__ inline unsigned pack_fp8x4(float a, float b, float c, float d) {
    int v = __builtin_amdgcn_cvt_pk_fp8_f32(a, b, 0, false);
    v = __builtin_amdgcn_cvt_pk_fp8_f32(c, d, v, true);
    return (unsigned)v;
}

// ---- K1: bucket histogram ----
__global__ __launch_bounds__(256) void bucket_count_kernel(
        const int* __restrict__ dst, int* __restrict__ bucketCnt, int E, int NB) {
    __shared__ int hist[MAXNB];
    int t = threadIdx.x;
    hist[t] = 0;
    __syncthreads();
    int start = blockIdx.x * CHUNK;
    int cnt = min(CHUNK, E - start);
    for (int i = t; i < cnt; i += 256) atomicAdd(&hist[dst[start + i] >> BSHIFT], 1);
    __syncthreads();
    if (t < NB && hist[t]) atomicAdd(&bucketCnt[t], hist[t]);
}

// ---- K2: scan bucket totals ----
__global__ __launch_bounds__(256) void bucket_scan_kernel(
        const int* __restrict__ bucketCnt, int* __restrict__ bucketBase,
        int* __restrict__ bucketCursor, int* __restrict__ offs, int NB, int N) {
    int t = threadIdx.x, lane = t & 63, wave = t >> 6;
    int v = (t < NB) ? bucketCnt[t] : 0;
    int s = v;
    for (int off = 1; off < 64; off <<= 1) {
        int u = __shfl_up(s, off, 64);
        if (lane >= off) s += u;
    }
    __shared__ int wsum[4];
    if (lane == 63) wsum[wave] = s;
    __syncthreads();
    if (t == 0) {
        int c = 0;
        for (int i = 0; i < 4; ++i) { int x = wsum[i]; wsum[i] = c; c += x; }
    }
    __syncthreads();
    int incl = wsum[wave] + s;
    int excl = incl - v;
    if (t < NB) { bucketBase[t] = excl; bucketCursor[t] = excl; }
    if (t == NB - 1) { bucketBase[NB] = incl; offs[N] = incl; }
}

// ---- K3: bucket-ordered scatter via LDS binning ----
__global__ __launch_bounds__(256) void bucket_scatter_kernel(
        const int* __restrict__ src, const int* __restrict__ dst,
        int* __restrict__ bucketCursor, int2* __restrict__ ebuf, int E) {
    __shared__ int hist[MAXNB], lofs[MAXNB], lcur[MAXNB], gbase[MAXNB];
    __shared__ int2 bin[CHUNK];
    int t = threadIdx.x, lane = t & 63, wave = t >> 6;
    int start = blockIdx.x * CHUNK;
    int cnt = min(CHUNK, E - start);
    hist[t] = 0;
    __syncthreads();
    for (int i = t; i < cnt; i += 256) atomicAdd(&hist[dst[start + i] >> BSHIFT], 1);
    __syncthreads();
    int v = hist[t];
    int s = v;
    for (int off = 1; off < 64; off <<= 1) {
        int u = __shfl_up(s, off, 64);
        if (lane >= off) s += u;
    }
    __shared__ int wsum[4];
    if (lane == 63) wsum[wave] = s;
    __syncthreads();
    if (t == 0) {
        int c = 0;
        for (int i = 0; i < 4; ++i) { int x = wsum[i]; wsum[i] = c; c += x; }
    }
    __syncthreads();
    int excl = wsum[wave] + s - v;
    lofs[t] = excl; lcur[t] = excl;
    if (v) gbase[t] = atomicAdd(&bucketCursor[t], v);
    __syncthreads();
    for (int i = t; i < cnt; i += 256) {
        int s0 = src[start + i], d0 = dst[start + i];
        int r = atomicAdd(&lcur[d0 >> BSHIFT], 1);
        bin[r] = make_int2(s0, d0);
    }
    __syncthreads();
    for (int i = t; i < cnt; i += 256) {
        int2 e = bin[i];
        int b = e.y >> BSHIFT;
        ebuf[gbase[b] + i - lofs[b]] = e;
    }
}

// ---- K4: per-bucket degrees -> offs, norm ----
__global__ __launch_bounds__(256) void build_norm_kernel(
        const int2* __restrict__ ebuf, const int* __restrict__ bucketBase,
        int* __restrict__ offs, float* __restrict__ norm, int N) {
    __shared__ int hist[BSZ];
    int b = blockIdx.x, t = threadIdx.x, lane = t & 63, wave = t >> 6;
    hist[t] = 0;
    __syncthreads();
    int segS = bucketBase[b], segE = bucketBase[b + 1];
    for (int i = segS + t; i < segE; i += 256) atomicAdd(&hist[ebuf[i].y & (BSZ - 1)], 1);
    __syncthreads();
    int v = hist[t];
    int s = v;
    for (int off = 1; off < 64; off <<= 1) {
        int u = __shfl_up(s, off, 64);
        if (lane >= off) s += u;
    }
    __shared__ int wsum[4];
    if (lane == 63) wsum[wave] = s;
    __syncthreads();
    if (t == 0) {
        int c = 0;
        for (int i = 0; i < 4; ++i) { int x = wsum[i]; wsum[i] = c; c += x; }
    }
    __syncthreads();
    int excl = wsum[wave] + s - v;
    int node = b * BSZ + t;
    if (node < N) {
        offs[node] = segS + excl;
        norm[node] = rsqrtf((float)(v > 0 ? v : 1));
    }
}

// ---- K5: per-bucket exact CSR placement with weights ----
__global__ __launch_bounds__(256) void build_csr_kernel(
        const int2* __restrict__ ebuf, const int* __restrict__ bucketBase,
        const int* __restrict__ offs, const float* __restrict__ norm,
        int2* __restrict__ csr, int N) {
    __shared__ int lcur[BSZ];
    __shared__ float snorm[BSZ];
    int b = blockIdx.x, t = threadIdx.x;
    int node = b * BSZ + t;
    lcur[t] = (node < N) ? offs[node] : 0;
    snorm[t] = (node < N) ? norm[node] : 0.f;
    __syncthreads();
    int segS = bucketBase[b], segE = bucketBase[b + 1];
    for (int i = segS + t; i < segE; i += 256) {
        int2 e = ebuf[i];
        int li = e.y & (BSZ - 1);
        float w = norm[e.x] * snorm[li];
        int p = atomicAdd(&lcur[li], 1);
        csr[p] = make_int2(e.x, __float_as_int(w));
    }
}

// ---- prep: feat fp32->fp8 cast + weight transpose/convert ----
__global__ void prep_kernel(const float* __restrict__ feat, unsigned* __restrict__ x0,
                            const float* __restrict__ W1, const float* __restrict__ W2,
                            unsigned short* __restrict__ W1T, unsigned short* __restrict__ W2T,
                            int nfeat_dw) {
    int i = blockIdx.x * blockDim.x + threadIdx.x;
    if (i < nfeat_dw) {                        // one fp8x4 dword from 4 floats
        float4 f = *(const float4*)(feat + (size_t)i * 4);
        x0[i] = pack_fp8x4(f.x, f.y, f.z, f.w);
        return;
    }
    int j = i - nfeat_dw;
    if (j < 256 * 128) {                       // W1T[n][k] = W1[k][n]
        int n = j >> 7, k = j & 127;
        W1T[j] = f2bf(W1[k * 256 + n]);
        return;
    }
    int k2 = j - 256 * 128;
    if (k2 < 48 * 256) {                       // W2T[c][k] = W2[k][c], pad c to 48
        int c = k2 >> 8, kk = k2 & 255;
        W2T[k2] = (c < 40) ? f2bf(W2[kk * 40 + c]) : (unsigned short)0;
    }
}

// fp8 row: 32 dwords (128 B). Quarter-wave: 16 lanes x uint2 (8 fp8 each).
#define ACC8(dd, ww)                                                         \
    {                                                                        \
        f32x2 p0 = __builtin_amdgcn_cvt_pk_f32_fp8((int)(dd).x, false);      \
        f32x2 p1 = __builtin_amdgcn_cvt_pk_f32_fp8((int)(dd).x, true);       \
        f32x2 p2 = __builtin_amdgcn_cvt_pk_f32_fp8((int)(dd).y, false);      \
        f32x2 p3 = __builtin_amdgcn_cvt_pk_f32_fp8((int)(dd).y, true);       \
        a0 += p0.x * (ww); a1 += p0.y * (ww);                                \
        a2 += p1.x * (ww); a3 += p1.y * (ww);                                \
        a4 += p2.x * (ww); a5 += p2.y * (ww);                                \
        a6 += p3.x * (ww); a7 += p3.y * (ww);                                \
    }

// ---- propagation (steps 1,2): wave per node, fp8 rows ----
__global__ __launch_bounds__(256) void prop_kernel(
        const unsigned* __restrict__ xin, unsigned* __restrict__ xout,
        const int* __restrict__ offs, const int2* __restrict__ csr, int N) {
    int t = threadIdx.x;
    int wv = t >> 6, lane = t & 63;
    int q = lane >> 4, ql = lane & 15;
    int v = blockIdx.x * 4 + wv;
    if (v >= N) return;
    __shared__ int2 sIW[4][64];
    int start = offs[v], end = offs[v + 1];
    float a0 = 0.f, a1 = 0.f, a2 = 0.f, a3 = 0.f;
    float a4 = 0.f, a5 = 0.f, a6 = 0.f, a7 = 0.f;
    for (int k = start; k < end; k += 64) {
        int cnt = min(64, end - k);
        if (lane < cnt) sIW[wv][lane] = csr[k + lane];   // same-wave LDS: ordered
        int j = 0;
        for (; j + 16 <= cnt; j += 16) {
            uint2 d[4]; float w[4];
#pragma unroll
            for (int u = 0; u < 4; ++u) {
                int2 e = sIW[wv][j + 4 * u + q];
                w[u] = __int_as_float(e.y);
                d[u] = *(const uint2*)(xin + (size_t)e.x * 32 + ql * 2);
            }
#pragma unroll
            for (int u = 0; u < 4; ++u) ACC8(d[u], w[u]);
        }
        if (j < cnt) {                         // masked final group, still 4-deep
            uint2 d[4]; float w[4];
#pragma unroll
            for (int u = 0; u < 4; ++u) {
                int idx = j + 4 * u + q;
                int2 e = sIW[wv][min(idx, cnt - 1)];
                w[u] = (idx < cnt) ? __int_as_float(e.y) : 0.f;
                d[u] = *(const uint2*)(xin + (size_t)e.x * 32 + ql * 2);
            }
#pragma unroll
            for (int u = 0; u < 4; ++u) ACC8(d[u], w[u]);
        }
    }
    a0 += __shfl_xor(a0, 16, 64); a0 += __shfl_xor(a0, 32, 64);
    a1 += __shfl_xor(a1, 16, 64); a1 += __shfl_xor(a1, 32, 64);
    a2 += __shfl_xor(a2, 16, 64); a2 += __shfl_xor(a2, 32, 64);
    a3 += __shfl_xor(a3, 16, 64); a3 += __shfl_xor(a3, 32, 64);
    a4 += __shfl_xor(a4, 16, 64); a4 += __shfl_xor(a4, 32, 64);
    a5 += __shfl_xor(a5, 16, 64); a5 += __shfl_xor(a5, 32, 64);
    a6 += __shfl_xor(a6, 16, 64); a6 += __shfl_xor(a6, 32, 64);
    a7 += __shfl_xor(a7, 16, 64); a7 += __shfl_xor(a7, 32, 64);
    if (q == 0) {
        uint2 o;
        o.x = pack_fp8x4(a0, a1, a2, a3);
        o.y = pack_fp8x4(a4, a5, a6, a7);
        *(uint2*)(xout + (size_t)v * 32 + ql * 2) = o;
    }
}

// ---- prop step 3 + average: ysum = (feat + x1 + x2 + x3) * 0.25 -> bf16 ----
__global__ __launch_bounds__(256) void prop3_sum_kernel(
        const unsigned* __restrict__ x2, const float* __restrict__ feat,
        const unsigned* __restrict__ x1, unsigned* __restrict__ ysum,
        const int* __restrict__ offs, const int2* __restrict__ csr, int N) {
    int t = threadIdx.x;
    int wv = t >> 6, lane = t & 63;
    int q = lane >> 4, ql = lane & 15;
    int v = blockIdx.x * 4 + wv;
    if (v >= N) return;
    __shared__ int2 sIW[4][64];
    int start = offs[v], end = offs[v + 1];
    float a0 = 0.f, a1 = 0.f, a2 = 0.f, a3 = 0.f;
    float a4 = 0.f, a5 = 0.f, a6 = 0.f, a7 = 0.f;
    for (int k = start; k < end; k += 64) {
        int cnt = min(64, end - k);
        if (lane < cnt) sIW[wv][lane] = csr[k + lane];
        int j = 0;
        for (; j + 16 <= cnt; j += 16) {
            uint2 d[4]; float w[4];
#pragma unroll
            for (int u = 0; u < 4; ++u) {
                int2 e = sIW[wv][j + 4 * u + q];
                w[u] = __int_as_float(e.y);
                d[u] = *(const uint2*)(x2 + (size_t)e.x * 32 + ql * 2);
            }
#pragma unroll
            for (int u = 0; u < 4; ++u) ACC8(d[u], w[u]);
        }
        if (j < cnt) {
            uint2 d[4]; float w[4];
#pragma unroll
            for (int u = 0; u < 4; ++u) {
                int idx = j + 4 * u + q;
                int2 e = sIW[wv][min(idx, cnt - 1)];
                w[u] = (idx < cnt) ? __int_as_float(e.y) : 0.f;
                d[u] = *(const uint2*)(x2 + (size_t)e.x * 32 + ql * 2);
            }
#pragma unroll
            for (int u = 0; u < 4; ++u) ACC8(d[u], w[u]);
        }
    }
    a0 += __shfl_xor(a0, 16, 64); a0 += __shfl_xor(a0, 32, 64);
    a1 += __shfl_xor(a1, 16, 64); a1 += __shfl_xor(a1, 32, 64);
    a2 += __shfl_xor(a2, 16, 64); a2 += __shfl_xor(a2, 32, 64);
    a3 += __shfl_xor(a3, 16, 64); a3 += __shfl_xor(a3, 32, 64);
    a4 += __shfl_xor(a4, 16, 64); a4 += __shfl_xor(a4, 32, 64);
    a5 += __shfl_xor(a5, 16, 64); a5 += __shfl_xor(a5, 32, 64);
    a6 += __shfl_xor(a6, 16, 64); a6 += __shfl_xor(a6, 32, 64);
    a7 += __shfl_xor(a7, 16, 64); a7 += __shfl_xor(a7, 32, 64);
    if (q == 0) {
        size_t fo = (size_t)v * 128 + ql * 8;
        float4 f0 = *(const float4*)(feat + fo);
        float4 f1 = *(const float4*)(feat + fo + 4);
        uint2 u1 = *(const uint2*)(x1 + (size_t)v * 32 + ql * 2);
        uint2 u2 = *(const uint2*)(x2 + (size_t)v * 32 + ql * 2);
        f32x2 q10 = __builtin_amdgcn_cvt_pk_f32_fp8((int)u1.x, false);
        f32x2 q11 = __builtin_amdgcn_cvt_pk_f32_fp8((int)u1.x, true);
        f32x2 q12 = __builtin_amdgcn_cvt_pk_f32_fp8((int)u1.y, false);
        f32x2 q13 = __builtin_amdgcn_cvt_pk_f32_fp8((int)u1.y, true);
        f32x2 q20 = __builtin_amdgcn_cvt_pk_f32_fp8((int)u2.x, false);
        f32x2 q21 = __builtin_amdgcn_cvt_pk_f32_fp8((int)u2.x, true);
        f32x2 q22 = __builtin_amdgcn_cvt_pk_f32_fp8((int)u2.y, false);
        f32x2 q23 = __builtin_amdgcn_cvt_pk_f32_fp8((int)u2.y, true);
        float s0 = (f0.x + q10.x + q20.x + a0) * 0.25f;
        float s1 = (f0.y + q10.y + q20.y + a1) * 0.25f;
        float s2 = (f0.z + q11.x + q21.x + a2) * 0.25f;
        float s3 = (f0.w + q11.y + q21.y + a3) * 0.25f;
        float s4 = (f1.x + q12.x + q22.x + a4) * 0.25f;
        float s5 = (f1.y + q12.y + q22.y + a5) * 0.25f;
        float s6 = (f1.z + q13.x + q23.x + a6) * 0.25f;
        float s7 = (f1.w + q13.y + q23.y + a7) * 0.25f;
        uint4 o;
        o.x = pack_bf16x2(s0, s1); o.y = pack_bf16x2(s2, s3);
        o.z = pack_bf16x2(s4, s5); o.w = pack_bf16x2(s6, s7);
        *(uint4*)(ysum + (size_t)v * 64 + ql * 4) = o;
    }
}

// ---- MLP on 16-node tiles ----
typedef __attribute__((ext_vector_type(8))) short bf16x8;
typedef __attribute__((ext_vector_type(4))) float f32x4;

#define SA_STRIDE 136   // 128 + 8 bf16 pad
#define SH_STRIDE 264   // 256 + 8 bf16 pad

__global__ __launch_bounds__(256) void mlp16_kernel(
        const unsigned* __restrict__ ysum,
        const unsigned short* __restrict__ W1T, const float* __restrict__ b1,
        const unsigned short* __restrict__ W2T, const float* __restrict__ b2,
        float* __restrict__ out, int N) {
    __shared__ unsigned short sA[16 * SA_STRIDE];
    __shared__ unsigned short sH[16 * SH_STRIDE];
    int t = threadIdx.x, wv = t >> 6, lane = t & 63;
    int l15 = lane & 15, lq = lane >> 4;
    int base = blockIdx.x * 16;

    {
        int n = t >> 4, sg = t & 15;
        int gv = base + n;
        uint4 u = make_uint4(0u, 0u, 0u, 0u);
        if (gv < N) u = *(const uint4*)(ysum + (size_t)gv * 64 + sg * 4);
        *(uint4*)&sA[n * SA_STRIDE + sg * 8] = u;
    }
    __syncthreads();

    f32x4 acc[4];
#pragma unroll
    for (int ht = 0; ht < 4; ++ht) acc[ht] = (f32x4){0.f, 0.f, 0.f, 0.f};
#pragma unroll
    for (int s = 0; s < 4; ++s) {
        bf16x8 afr = *(const bf16x8*)&sA[l15 * SA_STRIDE + s * 32 + lq * 8];
#pragma unroll
        for (int ht = 0; ht < 4; ++ht) {
            bf16x8 bfr = *(const bf16x8*)(W1T + ((wv * 64 + ht * 16 + l15) * 128 + s * 32 + lq * 8));
            acc[ht] = __builtin_amdgcn_mfma_f32_16x16x32_bf16(afr, bfr, acc[ht], 0, 0, 0);
        }
    }
#pragma unroll
    for (int ht = 0; ht < 4; ++ht) {
        int hid = wv * 64 + ht * 16 + l15;
        float bb = b1[hid];
#pragma unroll
        for (int r = 0; r < 4; ++r) {
            int node = lq * 4 + r;
            sH[node * SH_STRIDE + hid] = f2bf(fmaxf(acc[ht][r] + bb, 0.f));
        }
    }
    __syncthreads();
    if (wv != 0) return;

    f32x4 acc2[3];
#pragma unroll
    for (int ct = 0; ct < 3; ++ct) acc2[ct] = (f32x4){0.f, 0.f, 0.f, 0.f};
#pragma unroll
    for (int s = 0; s < 8; ++s) {
        bf16x8 afr = *(const bf16x8*)&sH[l15 * SH_STRIDE + s * 32 + lq * 8];
#pragma unroll
        for (int ct = 0; ct < 3; ++ct) {
            bf16x8 bfr = *(const bf16x8*)(W2T + ((ct * 16 + l15) * 256 + s * 32 + lq * 8));
            acc2[ct] = __builtin_amdgcn_mfma_f32_16x16x32_bf16(afr, bfr, acc2[ct], 0, 0, 0);
        }
    }

    float lg[3][4];
#pragma unroll
    for (int ct = 0; ct < 3; ++ct) {
        int c = ct * 16 + l15;
        float bb = (c < NCLS) ? b2[c] : 0.f;
#pragma unroll
        for (int r = 0; r < 4; ++r) lg[ct][r] = acc2[ct][r] + bb;
    }
#pragma unroll
    for (int r = 0; r < 4; ++r) {
        float m = fmaxf(lg[0][r], lg[1][r]);
        if (l15 < 8) m = fmaxf(m, lg[2][r]);
        for (int off = 1; off < 16; off <<= 1) m = fmaxf(m, __shfl_xor(m, off, 64));
        float ssum = __expf(lg[0][r] - m) + __expf(lg[1][r] - m) +
                     ((l15 < 8) ? __expf(lg[2][r] - m) : 0.f);
        for (int off = 1; off < 16; off <<= 1) ssum += __shfl_xor(ssum, off, 64);
        float ls = m + __logf(ssum);
        int node = base + lq * 4 + r;
        if (node < N) {
#pragma unroll
            for (int ct = 0; ct < 3; ++ct) {
                int c = ct * 16 + l15;
                if (c < NCLS) out[(size_t)node * NCLS + c] = lg[ct][r] - ls;
            }
        }
    }
}

extern "C" void kernel_launch(void* const* d_in, const int* in_sizes, int n_in,
                              void* d_out, int out_size, void* d_ws, size_t ws_size,
                              hipStream_t stream) {
    const float* feat = (const float*)d_in[0];
    const int*   src  = (const int*)d_in[1];
    const int*   dst  = (const int*)d_in[2];
    const float* W1   = (const float*)d_in[3];
    const float* b1   = (const float*)d_in[4];
    const float* W2   = (const float*)d_in[5];
    const float* b2   = (const float*)d_in[6];
    float* out = (float*)d_out;

    int N = in_sizes[0] / IN_DIM;
    int E = in_sizes[1];
    int NB = (N + BSZ - 1) / BSZ;

    char* ws = (char*)d_ws;
    size_t off = 0;
    float* norm   = (float*)(ws + off); off += align256((size_t)N * 4);
    int*   offs   = (int*)(ws + off);   off += align256((size_t)(N + 1) * 4);
    int*   bBase  = (int*)(ws + off);   off += align256((size_t)(MAXNB + 1) * 4);
    int*   bCur   = (int*)(ws + off);   off += align256((size_t)MAXNB * 4);
    int*   bCnt   = (int*)(ws + off);   off += align256((size_t)MAXNB * 4);
    int2*  csr    = (int2*)(ws + off);  off += align256((size_t)E * 8);
    unsigned* x0  = (unsigned*)(ws + off); off += align256((size_t)N * 32 * 4);  // fp8 rows
    unsigned* x1  = (unsigned*)(ws + off); off += align256((size_t)N * 32 * 4);
    unsigned* x2  = (unsigned*)(ws + off); off += align256((size_t)N * 32 * 4);
    unsigned* ysum = (unsigned*)(ws + off); off += align256((size_t)N * 64 * 4); // bf16 rows
    int2*  ebuf   = (int2*)(ws + off);  off += align256((size_t)E * 8);
    unsigned short* W1T = (unsigned short*)(ws + off); off += align256((size_t)256 * 128 * 2);
    unsigned short* W2T = (unsigned short*)(ws + off); off += align256((size_t)48 * 256 * 2);
    (void)ws_size;

    hipMemsetAsync(bCnt, 0, (size_t)MAXNB * 4, stream);

    int echunks = (E + CHUNK - 1) / CHUNK;
    bucket_count_kernel<<<echunks, 256, 0, stream>>>(dst, bCnt, E, NB);
    bucket_scan_kernel<<<1, 256, 0, stream>>>(bCnt, bBase, bCur, offs, NB, N);
    bucket_scatter_kernel<<<echunks, 256, 0, stream>>>(src, dst, bCur, ebuf, E);
    build_norm_kernel<<<NB, 256, 0, stream>>>(ebuf, bBase, offs, norm, N);
    build_csr_kernel<<<NB, 256, 0, stream>>>(ebuf, bBase, offs, norm, csr, N);

    int nprep = N * 32 + 256 * 128 + 48 * 256;
    prep_kernel<<<(nprep + 255) / 256, 256, 0, stream>>>(feat, x0, W1, W2, W1T, W2T, N * 32);

    int pb = (N + 3) / 4;
    prop_kernel<<<pb, 256, 0, stream>>>(x0, x1, offs, csr, N);
    prop_kernel<<<pb, 256, 0, stream>>>(x1, x2, offs, csr, N);
    prop3_sum_kernel<<<pb, 256, 0, stream>>>(x2, feat, x1, ysum, offs, csr, N);

    mlp16_kernel<<<(N + 15) / 16, 256, 0, stream>>>(ysum, W1T, b1, W2T, b2, out, N);
}